// Round 6
// baseline (157.623 us; speedup 1.0000x reference)
//
#include <hip/hip_runtime.h>
#include <hip/hip_bf16.h>
#include <math.h>

#define N_SPECIES 4
#define NNZ       16384
#define MPS       4096      // NNZ / N_SPECIES
#define N_CELLS   512
#define N_LATENT  256
#define HDIM      1024
#define N_GENES   20000

#define STRIPE    128                       // genes per bucket stripe
#define NSTRIPE   157                       // ceil(20000/128)
#define NBUCKET   (N_SPECIES * NSTRIPE)     // 628
#define CAP       128
#define KCHUNK    32                        // k-rows per staged chunk
#define KSLICE    64                        // k-rows per block (2 chunks)
#define NSLICE    (HDIM / KSLICE)           // 16
#define LDPAD     (STRIPE + 4)              // 132

typedef __bf16 bf16x8 __attribute__((ext_vector_type(8)));
typedef float  f32x4  __attribute__((ext_vector_type(4)));

static __device__ __forceinline__ unsigned short f2b(float f) {
    __hip_bfloat16 h = __float2bfloat16(f);
    return __builtin_bit_cast(unsigned short, h);
}
static __device__ __forceinline__ float softplusf(float x) {
    return (x > 20.f) ? x : log1pf(expf(x));
}

// ---------------------------------------------------------------------------
// Kernel 1: transpose + convert W (S, K, N) f32  ->  Wt (S, N, K) bf16
// ---------------------------------------------------------------------------
__global__ __launch_bounds__(256) void transpose_bf16(
    const float* __restrict__ W, unsigned short* __restrict__ Wt, int K, int N)
{
    __shared__ float tile[32][33];
    int s = blockIdx.z;
    const float* Ws = W + (size_t)s * K * N;
    unsigned short* Wts = Wt + (size_t)s * N * K;
    int n0 = blockIdx.x * 32, k0 = blockIdx.y * 32;
    int tx = threadIdx.x, ty = threadIdx.y;   // block (32, 8)
    #pragma unroll
    for (int p = 0; p < 4; p++)
        tile[ty + 8 * p][tx] = Ws[(size_t)(k0 + ty + 8 * p) * N + n0 + tx];
    __syncthreads();
    #pragma unroll
    for (int p = 0; p < 4; p++) {
        int r = ty + 8 * p;
        Wts[(size_t)(n0 + r) * K + k0 + tx] = f2b(tile[tx][r]);
    }
}

// ---------------------------------------------------------------------------
// Kernel 2: build combined input  A (S, 512, 512) bf16
// ---------------------------------------------------------------------------
__global__ __launch_bounds__(256) void build_combined(
    const float* __restrict__ z, const float* __restrict__ gl,
    const int* __restrict__ bidx, unsigned short* __restrict__ A)
{
    int idx = blockIdx.x * 256 + threadIdx.x;
    int c = idx & 511;
    int r = (idx >> 9) & 511;
    int s = idx >> 18;
    float v;
    if (c < N_LATENT)
        v = z[((size_t)s * MPS + r) * N_LATENT + c];
    else
        v = gl[(size_t)bidx[s * MPS + r] * N_LATENT + (c - N_LATENT)];
    A[idx] = f2b(v);
}

// ---------------------------------------------------------------------------
// Kernel 3: bf16 MFMA GEMM:  C = relu(A @ B + bias)
// Tile BM=BN=64, BK=64, 4 waves (2x2), wave = 32x32, XOR-swizzled LDS
// ---------------------------------------------------------------------------
__global__ __launch_bounds__(256) void gemm_bf16_mfma(
    const unsigned short* __restrict__ A, const unsigned short* __restrict__ Bt,
    const float* __restrict__ bias, void* __restrict__ Cptr,
    int M, int N, int K, int out_bf16)
{
    int s = blockIdx.z;
    const unsigned short* As = A  + (size_t)s * M * K;
    const unsigned short* Bs = Bt + (size_t)s * N * K;
    const float* bvec = bias + (size_t)s * N;

    int m0 = blockIdx.x * 64, n0 = blockIdx.y * 64;

    __shared__ unsigned short Alds[64 * 64];
    __shared__ unsigned short Blds[64 * 64];

    int tid  = threadIdx.x;
    int lane = tid & 63, w = tid >> 6;
    int wr = w >> 1, wc = w & 1;

    f32x4 acc[2][2] = {};

    for (int kt = 0; kt < K; kt += 64) {
        #pragma unroll
        for (int it = 0; it < 2; it++) {
            int c   = it * 256 + tid;
            int row = c >> 3, kb = c & 7;
            int pa  = kb ^ (row & 7);
            uint4 va = *(const uint4*)(As + (size_t)(m0 + row) * K + kt + kb * 8);
            *(uint4*)(Alds + row * 64 + pa * 8) = va;
            uint4 vb = *(const uint4*)(Bs + (size_t)(n0 + row) * K + kt + kb * 8);
            *(uint4*)(Blds + row * 64 + pa * 8) = vb;
        }
        __syncthreads();
        #pragma unroll
        for (int ks = 0; ks < 2; ks++) {
            bf16x8 af[2], bfr[2];
            #pragma unroll
            for (int f = 0; f < 2; f++) {
                int ar  = wr * 32 + f * 16 + (lane & 15);
                int akb = (ks * 4 + (lane >> 4)) ^ (ar & 7);
                af[f]  = __builtin_bit_cast(bf16x8, *(const uint4*)(Alds + ar * 64 + akb * 8));
                int br  = wc * 32 + f * 16 + (lane & 15);
                int bkb = (ks * 4 + (lane >> 4)) ^ (br & 7);
                bfr[f] = __builtin_bit_cast(bf16x8, *(const uint4*)(Blds + br * 64 + bkb * 8));
            }
            #pragma unroll
            for (int fm = 0; fm < 2; fm++)
                #pragma unroll
                for (int fn = 0; fn < 2; fn++)
                    acc[fm][fn] = __builtin_amdgcn_mfma_f32_16x16x32_bf16(
                        af[fm], bfr[fn], acc[fm][fn], 0, 0, 0);
        }
        __syncthreads();
    }

    #pragma unroll
    for (int fm = 0; fm < 2; fm++)
        #pragma unroll
        for (int fn = 0; fn < 2; fn++) {
            int col = n0 + wc * 32 + fn * 16 + (lane & 15);
            float bv = bvec[col];
            #pragma unroll
            for (int r = 0; r < 4; r++) {
                int row = m0 + wr * 32 + fm * 16 + (lane >> 4) * 4 + r;
                float v = acc[fm][fn][r] + bv;
                v = fmaxf(v, 0.0f);
                size_t off = (size_t)s * M * N + (size_t)row * N + col;
                if (out_bf16) ((unsigned short*)Cptr)[off] = f2b(v);
                else          ((float*)Cptr)[off] = v;
            }
        }
}

// ---------------------------------------------------------------------------
// Kernel 4a: zero bucket counters, overflow counter, and partial buffer
// ---------------------------------------------------------------------------
__global__ __launch_bounds__(256) void zero_aux(
    int* __restrict__ counts, float* __restrict__ partial)
{
    int i = blockIdx.x * 256 + threadIdx.x;
    if (i <= NBUCKET) counts[i] = 0;          // [NBUCKET] = overflow counter
    if (i < NSLICE * NNZ) partial[i] = 0.f;
}

// ---------------------------------------------------------------------------
// Kernel 4b: bucket entries by (species, 128-gene stripe)
// ---------------------------------------------------------------------------
__global__ __launch_bounds__(256) void bucket_entries(
    const int* __restrict__ gidx, int* __restrict__ counts,
    int* __restrict__ lists, int* __restrict__ ovf_list)
{
    int j = blockIdx.x * 256 + threadIdx.x;
    int s = j >> 12;
    int sb = s * NSTRIPE + (gidx[j] >> 7);
    int pos = atomicAdd(&counts[sb], 1);
    if (pos < CAP) lists[sb * CAP + pos] = j;
    else           ovf_list[atomicAdd(&counts[NBUCKET], 1)] = j;
}

// ---------------------------------------------------------------------------
// Kernel 5: k-sliced stripe decode.
// Grid (NBUCKET, NSLICE=16): each block = (species, 128-gene stripe) x 64-row
// k-slice. Block stages 2 chunks of 32x128 W3 (16 KB each), computes 64-k
// partial dots for its bucket's entries, writes partial[slice][j], exits.
// Short blocks + slice-major dispatch => in-flight blocks cover the full
// gene width of one k-window => near-sequential HBM traffic (like the
// transpose kernel that sustained ~5.5 TB/s on this same pattern).
// ---------------------------------------------------------------------------
__global__ __launch_bounds__(256) void decode_slice(
    const float* __restrict__ H2, const int* __restrict__ bidx,
    const int* __restrict__ gidx, const float* __restrict__ W3,
    const int* __restrict__ counts, const int* __restrict__ lists,
    float* __restrict__ partial)
{
    __shared__ float tile[KCHUNK][LDPAD];      // 32 x 132 f32 = 16.9 KB
    int sb = blockIdx.x;
    int sl = blockIdx.y;
    int s  = sb / NSTRIPE;
    int g0 = (sb % NSTRIPE) * STRIPE;
    int cnt = counts[sb];
    cnt = (cnt < CAP) ? cnt : CAP;
    if (cnt == 0) return;

    const float* Ws = W3 + (size_t)s * HDIM * N_GENES;
    int tid = threadIdx.x, lane = tid & 63, w = tid >> 6;
    int hw = lane >> 5, l32 = lane & 31;
    int k0 = sl * KSLICE;

    for (int base = 0; base < cnt; base += 64) {
        int jj[8], gg[8];
        const float* hp[8];
        #pragma unroll
        for (int e = 0; e < 8; e++) {
            int li = base + e * 8 + w * 2 + hw;
            if (li < cnt) {
                int j = lists[sb * CAP + li];
                jj[e] = j;
                hp[e] = H2 + ((size_t)s * N_CELLS + bidx[j]) * HDIM + k0;
                gg[e] = gidx[j] - g0;
            } else jj[e] = -1;
        }
        float acc[8] = {};

        #pragma unroll
        for (int kc = 0; kc < KSLICE; kc += KCHUNK) {   // 2 chunks
            // ---- stage 32x128 panel: 512B contiguous per 32-lane row visit
            #pragma unroll
            for (int p = 0; p < 4; p++) {
                int i4 = tid + p * 256;
                int r = i4 >> 5, c4 = (i4 & 31) * 4;
                int gc = g0 + c4;
                gc = (gc <= N_GENES - 4) ? gc : (N_GENES - 4);   // tail clamp
                float4 v = *(const float4*)(Ws + (size_t)(k0 + kc + r) * N_GENES + gc);
                *(float4*)&tile[r][c4] = v;
            }
            __syncthreads();
            #pragma unroll
            for (int e = 0; e < 8; e++)
                if (jj[e] >= 0)
                    acc[e] += hp[e][kc + l32] * tile[l32][gg[e]];
            __syncthreads();
        }

        #pragma unroll
        for (int e = 0; e < 8; e++) {
            float sum = acc[e];
            sum += __shfl_xor(sum, 16, 64);   // masks <=16 stay in 32-lane half
            sum += __shfl_xor(sum,  8, 64);
            sum += __shfl_xor(sum,  4, 64);
            sum += __shfl_xor(sum,  2, 64);
            sum += __shfl_xor(sum,  1, 64);
            if (jj[e] >= 0 && l32 == 0)
                partial[(size_t)sl * NNZ + jj[e]] = sum;
        }
    }
}

// ---------------------------------------------------------------------------
// Kernel 6: overflow fallback — writes full dot into partial[0][j]
// (all other slices of an overflow entry remain zero)
// ---------------------------------------------------------------------------
__global__ __launch_bounds__(256) void decode_overflow(
    const float* __restrict__ H2, const int* __restrict__ bidx,
    const int* __restrict__ gidx, const float* __restrict__ W3,
    const int* __restrict__ counts, const int* __restrict__ ovf_list,
    float* __restrict__ partial)
{
    int n = counts[NBUCKET];
    int lane = threadIdx.x & 63;
    for (int i = blockIdx.x * 4 + (threadIdx.x >> 6); i < n; i += gridDim.x * 4) {
        int j = ovf_list[i];
        int s = j >> 12;
        int bi = bidx[j], gi = gidx[j];
        const float* h    = H2 + ((size_t)s * N_CELLS + bi) * HDIM;
        const float* wcol = W3 + (size_t)s * HDIM * N_GENES + gi;
        float sum = 0.f;
        #pragma unroll
        for (int t = 0; t < HDIM / 64; t++) {
            int k = t * 64 + lane;
            sum += h[k] * wcol[(size_t)k * N_GENES];
        }
        #pragma unroll
        for (int off = 32; off; off >>= 1)
            sum += __shfl_xor(sum, off, 64);
        if (lane == 0) partial[j] = sum;
    }
}

// ---------------------------------------------------------------------------
// Kernel 7: finalize  out[j] = softplus(sum_sl partial[sl][j] + b3[s][gi[j]])
// ---------------------------------------------------------------------------
__global__ __launch_bounds__(256) void finalize_out(
    const float* __restrict__ partial, const int* __restrict__ gidx,
    const float* __restrict__ b3, float* __restrict__ out)
{
    int j = blockIdx.x * 256 + threadIdx.x;
    int s = j >> 12;
    float x = b3[(size_t)s * N_GENES + gidx[j]];
    #pragma unroll
    for (int sl = 0; sl < NSLICE; sl++)
        x += partial[(size_t)sl * NNZ + j];
    out[j] = softplusf(x);
}

// ---------------------------------------------------------------------------
extern "C" void kernel_launch(void* const* d_in, const int* in_sizes, int n_in,
                              void* d_out, int out_size, void* d_ws, size_t ws_size,
                              hipStream_t stream) {
    const int*   batch_idx = (const int*)  d_in[1];
    const int*   gene_idx  = (const int*)  d_in[2];
    const float* gl        = (const float*)d_in[3];
    const float* z         = (const float*)d_in[4];
    const float* W1        = (const float*)d_in[5];
    const float* b1        = (const float*)d_in[6];
    const float* W2        = (const float*)d_in[7];
    const float* b2        = (const float*)d_in[8];
    const float* W3        = (const float*)d_in[9];
    const float* b3        = (const float*)d_in[10];
    float* out = (float*)d_out;

    char* ws = (char*)d_ws;
    unsigned short* Wt1  = (unsigned short*)(ws + 0);                 //  4 MB
    unsigned short* Wt2  = (unsigned short*)(ws + (4ull  << 20));     //  8 MB
    unsigned short* Acmb = (unsigned short*)(ws + (12ull << 20));     //  2 MB
    unsigned short* H1   = (unsigned short*)(ws + (14ull << 20));     //  4 MB
    float*          H2   = (float*)        (ws + (18ull << 20));      //  8 MB
    int*            counts   = (int*)      (ws + (26ull << 20));      // 629 ints
    int*            lists    = (int*)      (ws + (27ull << 20));      // 628*128 ints
    int*            ovf_list = (int*)      (ws + (28ull << 20));      // NNZ ints
    float*          partial  = (float*)    (ws + (29ull << 20));      // 16*NNZ f32 (1 MB)

    // --- bucket entries by (species, gene stripe); zero partials
    zero_aux<<<(NSLICE * NNZ + 255) / 256, 256, 0, stream>>>(counts, partial);
    bucket_entries<<<NNZ / 256, 256, 0, stream>>>(gene_idx, counts, lists, ovf_list);

    // --- weight transposes (f32 -> bf16, n-major) for the MLP
    transpose_bf16<<<dim3(HDIM / 32, (2 * N_LATENT) / 32, N_SPECIES), dim3(32, 8), 0, stream>>>(
        W1, Wt1, 2 * N_LATENT, HDIM);
    transpose_bf16<<<dim3(HDIM / 32, HDIM / 32, N_SPECIES), dim3(32, 8), 0, stream>>>(
        W2, Wt2, HDIM, HDIM);

    // --- combined input (concat z rows with gathered global latent)
    build_combined<<<(N_SPECIES * N_CELLS * 2 * N_LATENT) / 256, 256, 0, stream>>>(
        z, gl, batch_idx, Acmb);

    // --- layer 1: H1 = relu(Acmb @ W1 + b1)   M=512 K=512 N=1024, bf16 out
    gemm_bf16_mfma<<<dim3(N_CELLS / 64, HDIM / 64, N_SPECIES), 256, 0, stream>>>(
        Acmb, Wt1, b1, H1, N_CELLS, HDIM, 2 * N_LATENT, 1);

    // --- layer 2: H2 = relu(H1 @ W2 + b2)     M=512 K=1024 N=1024, f32 out
    gemm_bf16_mfma<<<dim3(N_CELLS / 64, HDIM / 64, N_SPECIES), 256, 0, stream>>>(
        H1, Wt2, b2, H2, N_CELLS, HDIM, HDIM, 0);

    // --- k-sliced fused decode: short blocks, slice-major dispatch
    decode_slice<<<dim3(NBUCKET, NSLICE), 256, 0, stream>>>(
        H2, batch_idx, gene_idx, W3, counts, lists, partial);
    decode_overflow<<<32, 256, 0, stream>>>(
        H2, batch_idx, gene_idx, W3, counts, ovf_list, partial);
    finalize_out<<<NNZ / 256, 256, 0, stream>>>(partial, gene_idx, b3, out);
}

// Round 7
// 144.073 us; speedup vs baseline: 1.0940x; 1.0940x over previous
//
#include <hip/hip_runtime.h>
#include <hip/hip_bf16.h>
#include <math.h>

#define N_SPECIES 4
#define NNZ       16384
#define MPS       4096      // NNZ / N_SPECIES
#define N_CELLS   512
#define N_LATENT  256
#define HDIM      1024
#define N_GENES   20000

#define STRIPE    128                       // genes per bucket stripe
#define NSTRIPE   157                       // ceil(20000/128)
#define NBUCKET   (N_SPECIES * NSTRIPE)     // 628
#define CAP       128
#define KCHUNK    32                        // k-rows per staged chunk
#define KSLICE    64                        // k-rows per decode block
#define NSLICE    (HDIM / KSLICE)           // 16
#define LDPAD     (STRIPE + 4)              // 132

typedef __bf16 bf16x8 __attribute__((ext_vector_type(8)));
typedef float  f32x4  __attribute__((ext_vector_type(4)));

static __device__ __forceinline__ unsigned short f2b(float f) {
    __hip_bfloat16 h = __float2bfloat16(f);
    return __builtin_bit_cast(unsigned short, h);
}
static __device__ __forceinline__ float b2f(unsigned short u) {
    return __builtin_bit_cast(float, (unsigned int)u << 16);
}
static __device__ __forceinline__ float softplusf(float x) {
    return (x > 20.f) ? x : log1pf(expf(x));
}

// ---------------------------------------------------------------------------
// Kernel 1: both weight transposes in ONE launch.
// y<16: W1 (512x1024) -> Wt1 (1024x512) bf16 ; y>=16: W2 (1024x1024) -> Wt2
// ---------------------------------------------------------------------------
__global__ __launch_bounds__(256) void transpose_w12(
    const float* __restrict__ W1, const float* __restrict__ W2,
    unsigned short* __restrict__ Wt1, unsigned short* __restrict__ Wt2)
{
    __shared__ float tile[32][33];
    int s = blockIdx.z, y = blockIdx.y;
    const float* Ws; unsigned short* Wts; int K, k0;
    if (y < 16) { Ws = W1 + (size_t)s * 512 * HDIM;  Wts = Wt1 + (size_t)s * HDIM * 512;  K = 512;  k0 = y * 32; }
    else        { Ws = W2 + (size_t)s * HDIM * HDIM; Wts = Wt2 + (size_t)s * HDIM * HDIM; K = HDIM; k0 = (y - 16) * 32; }
    int n0 = blockIdx.x * 32;
    int tx = threadIdx.x, ty = threadIdx.y;   // block (32, 8)
    #pragma unroll
    for (int p = 0; p < 4; p++)
        tile[ty + 8 * p][tx] = Ws[(size_t)(k0 + ty + 8 * p) * HDIM + n0 + tx];
    __syncthreads();
    #pragma unroll
    for (int p = 0; p < 4; p++) {
        int r = ty + 8 * p;
        Wts[(size_t)(n0 + r) * K + k0 + tx] = f2b(tile[tx][r]);
    }
}

// ---------------------------------------------------------------------------
// Kernel 2: GEMM layer 1 with FUSED input build.
// A[row][col] = col<256 ? z[s][row][col] : gl[bidx[s][row]][col-256], bf16'd
// in-staging. H1 = relu(A @ W1t + b1), bf16 out. M=512,N=1024,K=512.
// ---------------------------------------------------------------------------
__global__ __launch_bounds__(256) void gemm1_fused(
    const float* __restrict__ z, const float* __restrict__ gl,
    const int* __restrict__ bidx, const unsigned short* __restrict__ Bt,
    const float* __restrict__ bias, unsigned short* __restrict__ C)
{
    int s = blockIdx.z;
    const unsigned short* Bs = Bt + (size_t)s * HDIM * 512;
    const float* bvec = bias + (size_t)s * HDIM;
    int m0 = blockIdx.x * 64, n0 = blockIdx.y * 64;

    __shared__ unsigned short Alds[64 * 64];
    __shared__ unsigned short Blds[64 * 64];

    int tid = threadIdx.x, lane = tid & 63, w = tid >> 6;
    int wr = w >> 1, wc = w & 1;
    f32x4 acc[2][2] = {};

    for (int kt = 0; kt < 512; kt += 64) {
        #pragma unroll
        for (int it = 0; it < 2; it++) {
            int c = it * 256 + tid;
            int row = c >> 3, kb = c & 7;
            int pa = kb ^ (row & 7);
            int col = kt + kb * 8;
            const float* src;
            if (col < N_LATENT)
                src = z + ((size_t)s * MPS + m0 + row) * N_LATENT + col;
            else
                src = gl + (size_t)bidx[s * MPS + m0 + row] * N_LATENT + (col - N_LATENT);
            float4 f0 = *(const float4*)src;
            float4 f1 = *(const float4*)(src + 4);
            unsigned short o[8] = { f2b(f0.x), f2b(f0.y), f2b(f0.z), f2b(f0.w),
                                    f2b(f1.x), f2b(f1.y), f2b(f1.z), f2b(f1.w) };
            *(uint4*)(Alds + row * 64 + pa * 8) = *(const uint4*)o;
            uint4 vb = *(const uint4*)(Bs + (size_t)(n0 + row) * 512 + kt + kb * 8);
            *(uint4*)(Blds + row * 64 + pa * 8) = vb;
        }
        __syncthreads();
        #pragma unroll
        for (int ks = 0; ks < 2; ks++) {
            bf16x8 af[2], bfr[2];
            #pragma unroll
            for (int f = 0; f < 2; f++) {
                int ar  = wr * 32 + f * 16 + (lane & 15);
                int akb = (ks * 4 + (lane >> 4)) ^ (ar & 7);
                af[f]  = __builtin_bit_cast(bf16x8, *(const uint4*)(Alds + ar * 64 + akb * 8));
                int br  = wc * 32 + f * 16 + (lane & 15);
                int bkb = (ks * 4 + (lane >> 4)) ^ (br & 7);
                bfr[f] = __builtin_bit_cast(bf16x8, *(const uint4*)(Blds + br * 64 + bkb * 8));
            }
            #pragma unroll
            for (int fm = 0; fm < 2; fm++)
                #pragma unroll
                for (int fn = 0; fn < 2; fn++)
                    acc[fm][fn] = __builtin_amdgcn_mfma_f32_16x16x32_bf16(
                        af[fm], bfr[fn], acc[fm][fn], 0, 0, 0);
        }
        __syncthreads();
    }

    #pragma unroll
    for (int fm = 0; fm < 2; fm++)
        #pragma unroll
        for (int fn = 0; fn < 2; fn++) {
            int col = n0 + wc * 32 + fn * 16 + (lane & 15);
            float bv = bvec[col];
            #pragma unroll
            for (int r = 0; r < 4; r++) {
                int row = m0 + wr * 32 + fm * 16 + (lane >> 4) * 4 + r;
                float v = fmaxf(acc[fm][fn][r] + bv, 0.0f);
                C[(size_t)s * N_CELLS * HDIM + (size_t)row * HDIM + col] = f2b(v);
            }
        }
}

// ---------------------------------------------------------------------------
// Kernel 3: generic bf16 MFMA GEMM (layer 2): C = relu(A @ Bt + bias), bf16 out
// ---------------------------------------------------------------------------
__global__ __launch_bounds__(256) void gemm_bf16_mfma(
    const unsigned short* __restrict__ A, const unsigned short* __restrict__ Bt,
    const float* __restrict__ bias, unsigned short* __restrict__ C,
    int M, int N, int K)
{
    int s = blockIdx.z;
    const unsigned short* As = A  + (size_t)s * M * K;
    const unsigned short* Bs = Bt + (size_t)s * N * K;
    const float* bvec = bias + (size_t)s * N;
    int m0 = blockIdx.x * 64, n0 = blockIdx.y * 64;

    __shared__ unsigned short Alds[64 * 64];
    __shared__ unsigned short Blds[64 * 64];

    int tid = threadIdx.x, lane = tid & 63, w = tid >> 6;
    int wr = w >> 1, wc = w & 1;
    f32x4 acc[2][2] = {};

    for (int kt = 0; kt < K; kt += 64) {
        #pragma unroll
        for (int it = 0; it < 2; it++) {
            int c = it * 256 + tid;
            int row = c >> 3, kb = c & 7;
            int pa = kb ^ (row & 7);
            uint4 va = *(const uint4*)(As + (size_t)(m0 + row) * K + kt + kb * 8);
            *(uint4*)(Alds + row * 64 + pa * 8) = va;
            uint4 vb = *(const uint4*)(Bs + (size_t)(n0 + row) * K + kt + kb * 8);
            *(uint4*)(Blds + row * 64 + pa * 8) = vb;
        }
        __syncthreads();
        #pragma unroll
        for (int ks = 0; ks < 2; ks++) {
            bf16x8 af[2], bfr[2];
            #pragma unroll
            for (int f = 0; f < 2; f++) {
                int ar  = wr * 32 + f * 16 + (lane & 15);
                int akb = (ks * 4 + (lane >> 4)) ^ (ar & 7);
                af[f]  = __builtin_bit_cast(bf16x8, *(const uint4*)(Alds + ar * 64 + akb * 8));
                int br  = wc * 32 + f * 16 + (lane & 15);
                int bkb = (ks * 4 + (lane >> 4)) ^ (br & 7);
                bfr[f] = __builtin_bit_cast(bf16x8, *(const uint4*)(Blds + br * 64 + bkb * 8));
            }
            #pragma unroll
            for (int fm = 0; fm < 2; fm++)
                #pragma unroll
                for (int fn = 0; fn < 2; fn++)
                    acc[fm][fn] = __builtin_amdgcn_mfma_f32_16x16x32_bf16(
                        af[fm], bfr[fn], acc[fm][fn], 0, 0, 0);
        }
        __syncthreads();
    }

    #pragma unroll
    for (int fm = 0; fm < 2; fm++)
        #pragma unroll
        for (int fn = 0; fn < 2; fn++) {
            int col = n0 + wc * 32 + fn * 16 + (lane & 15);
            float bv = bvec[col];
            #pragma unroll
            for (int r = 0; r < 4; r++) {
                int row = m0 + wr * 32 + fm * 16 + (lane >> 4) * 4 + r;
                float v = fmaxf(acc[fm][fn][r] + bv, 0.0f);
                C[(size_t)s * M * N + (size_t)row * N + col] = f2b(v);
            }
        }
}

// ---------------------------------------------------------------------------
// Kernel 4a: zero bucket counters + overflow counter + partial buffer
// ---------------------------------------------------------------------------
__global__ __launch_bounds__(256) void zero_aux(
    int* __restrict__ counts, float* __restrict__ partial)
{
    int i = blockIdx.x * 256 + threadIdx.x;
    if (i <= NBUCKET) counts[i] = 0;          // [NBUCKET] = overflow counter
    if (i < NSLICE * NNZ) partial[i] = 0.f;
}

// ---------------------------------------------------------------------------
// Kernel 4b: bucket entries; pack (j, bi, gi) so decode has a 2-load chain
// ---------------------------------------------------------------------------
__global__ __launch_bounds__(256) void bucket_pack(
    const int* __restrict__ bidx, const int* __restrict__ gidx,
    int* __restrict__ counts, int4* __restrict__ lists4, int* __restrict__ ovf_list)
{
    int j = blockIdx.x * 256 + threadIdx.x;
    int s = j >> 12;
    int g = gidx[j];
    int sb = s * NSTRIPE + (g >> 7);
    int pos = atomicAdd(&counts[sb], 1);
    if (pos < CAP) lists4[sb * CAP + pos] = make_int4(j, bidx[j], g, 0);
    else           ovf_list[atomicAdd(&counts[NBUCKET], 1)] = j;
}

// ---------------------------------------------------------------------------
// Kernel 5: k-sliced stripe decode (+ fused overflow fallback on y==0 blocks).
// Grid (NBUCKET, NSLICE): block stages 2x 32x128 W3 panels, computes 64-k
// partial dots against bf16 H2, writes partial[slice][j].
// ---------------------------------------------------------------------------
__global__ __launch_bounds__(256) void decode_slice(
    const unsigned short* __restrict__ H2b, const int* __restrict__ bidx,
    const int* __restrict__ gidx, const float* __restrict__ W3,
    const int* __restrict__ counts, const int4* __restrict__ lists4,
    const int* __restrict__ ovf_list, float* __restrict__ partial)
{
    __shared__ float tile[KCHUNK][LDPAD];      // 32 x 132 f32 = 16.9 KB
    int sb = blockIdx.x, sl = blockIdx.y;
    int s  = sb / NSTRIPE;
    int g0 = (sb % NSTRIPE) * STRIPE;
    int tid = threadIdx.x, lane = tid & 63, w = tid >> 6;
    int hw = lane >> 5, l32 = lane & 31;
    int k0 = sl * KSLICE;
    const float* Ws = W3 + (size_t)s * HDIM * N_GENES;

    // ---- overflow fallback (statistically empty), wave-per-entry, full k
    if (sl == 0) {
        int novf = counts[NBUCKET];
        for (int i = sb * 4 + w; i < novf; i += NBUCKET * 4) {
            int j = ovf_list[i];
            int es = j >> 12;
            int bi = bidx[j], gi = gidx[j];
            const unsigned short* h = H2b + ((size_t)es * N_CELLS + bi) * HDIM;
            const float* wcol = W3 + (size_t)es * HDIM * N_GENES + gi;
            float sum = 0.f;
            #pragma unroll
            for (int t = 0; t < HDIM / 64; t++) {
                int k = t * 64 + lane;
                sum += b2f(h[k]) * wcol[(size_t)k * N_GENES];
            }
            #pragma unroll
            for (int off = 32; off; off >>= 1)
                sum += __shfl_xor(sum, off, 64);
            if (lane == 0) partial[j] = sum;
        }
    }

    int cnt = counts[sb];
    cnt = (cnt < CAP) ? cnt : CAP;
    if (cnt == 0) return;

    for (int base = 0; base < cnt; base += 64) {
        int jj[8], gg[8];
        const unsigned short* hp[8];
        #pragma unroll
        for (int e = 0; e < 8; e++) {
            int li = base + e * 8 + w * 2 + hw;
            if (li < cnt) {
                int4 L = lists4[sb * CAP + li];
                jj[e] = L.x;
                hp[e] = H2b + ((size_t)s * N_CELLS + L.y) * HDIM + k0;
                gg[e] = L.z & (STRIPE - 1);
            } else jj[e] = -1;
        }
        float acc[8] = {};

        #pragma unroll
        for (int kc = 0; kc < KSLICE; kc += KCHUNK) {   // 2 chunks
            #pragma unroll
            for (int p = 0; p < 4; p++) {
                int i4 = tid + p * 256;
                int r = i4 >> 5, c4 = (i4 & 31) * 4;
                int gc = g0 + c4;
                gc = (gc <= N_GENES - 4) ? gc : (N_GENES - 4);   // tail clamp
                float4 v = *(const float4*)(Ws + (size_t)(k0 + kc + r) * N_GENES + gc);
                *(float4*)&tile[r][c4] = v;
            }
            __syncthreads();
            #pragma unroll
            for (int e = 0; e < 8; e++)
                if (jj[e] >= 0)
                    acc[e] += b2f(hp[e][kc + l32]) * tile[l32][gg[e]];
            __syncthreads();
        }

        #pragma unroll
        for (int e = 0; e < 8; e++) {
            float sum = acc[e];
            sum += __shfl_xor(sum, 16, 64);   // masks <=16 stay in 32-lane half
            sum += __shfl_xor(sum,  8, 64);
            sum += __shfl_xor(sum,  4, 64);
            sum += __shfl_xor(sum,  2, 64);
            sum += __shfl_xor(sum,  1, 64);
            if (jj[e] >= 0 && l32 == 0)
                partial[(size_t)sl * NNZ + jj[e]] = sum;
        }
    }
}

// ---------------------------------------------------------------------------
// Kernel 6: finalize  out[j] = softplus(sum_sl partial[sl][j] + b3[s][gi[j]])
// ---------------------------------------------------------------------------
__global__ __launch_bounds__(256) void finalize_out(
    const float* __restrict__ partial, const int* __restrict__ gidx,
    const float* __restrict__ b3, float* __restrict__ out)
{
    int j = blockIdx.x * 256 + threadIdx.x;
    int s = j >> 12;
    float x = b3[(size_t)s * N_GENES + gidx[j]];
    #pragma unroll
    for (int sl = 0; sl < NSLICE; sl++)
        x += partial[(size_t)sl * NNZ + j];
    out[j] = softplusf(x);
}

// ---------------------------------------------------------------------------
extern "C" void kernel_launch(void* const* d_in, const int* in_sizes, int n_in,
                              void* d_out, int out_size, void* d_ws, size_t ws_size,
                              hipStream_t stream) {
    const int*   batch_idx = (const int*)  d_in[1];
    const int*   gene_idx  = (const int*)  d_in[2];
    const float* gl        = (const float*)d_in[3];
    const float* z         = (const float*)d_in[4];
    const float* W1        = (const float*)d_in[5];
    const float* b1        = (const float*)d_in[6];
    const float* W2        = (const float*)d_in[7];
    const float* b2        = (const float*)d_in[8];
    const float* W3        = (const float*)d_in[9];
    const float* b3        = (const float*)d_in[10];
    float* out = (float*)d_out;

    char* ws = (char*)d_ws;
    unsigned short* Wt1   = (unsigned short*)(ws + 0);                //  4 MB (4,1024,512)
    unsigned short* Wt2   = (unsigned short*)(ws + (4ull  << 20));    //  8 MB (4,1024,1024)
    unsigned short* H1    = (unsigned short*)(ws + (12ull << 20));    //  4 MB (4,512,1024) bf16
    unsigned short* H2b   = (unsigned short*)(ws + (16ull << 20));    //  4 MB (4,512,1024) bf16
    int*            counts   = (int*)       (ws + (20ull << 20));     // 629 ints
    int4*           lists4   = (int4*)      (ws + (21ull << 20));     // 628*128 int4 (1.3 MB)
    int*            ovf_list = (int*)       (ws + (23ull << 20));     // NNZ ints
    float*          partial  = (float*)     (ws + (24ull << 20));     // 16*NNZ f32 (1 MB)

    // 1) zero aux; bucket entries (packed j/bi/gi)
    zero_aux<<<(NSLICE * NNZ + 255) / 256, 256, 0, stream>>>(counts, partial);
    bucket_pack<<<NNZ / 256, 256, 0, stream>>>(batch_idx, gene_idx, counts, lists4, ovf_list);

    // 2) both weight transposes, one launch
    transpose_w12<<<dim3(HDIM / 32, 48, N_SPECIES), dim3(32, 8), 0, stream>>>(W1, W2, Wt1, Wt2);

    // 3) layer 1 with fused input build: H1 = relu([z|gl[bidx]] @ W1 + b1)
    gemm1_fused<<<dim3(N_CELLS / 64, HDIM / 64, N_SPECIES), 256, 0, stream>>>(
        z, gl, batch_idx, Wt1, b1, H1);

    // 4) layer 2: H2 = relu(H1 @ W2 + b2), bf16 out
    gemm_bf16_mfma<<<dim3(N_CELLS / 64, HDIM / 64, N_SPECIES), 256, 0, stream>>>(
        H1, Wt2, b2, H2b, N_CELLS, HDIM, HDIM);

    // 5) k-sliced fused decode (+ overflow fallback inside)
    decode_slice<<<dim3(NBUCKET, NSLICE), 256, 0, stream>>>(
        H2b, batch_idx, gene_idx, W3, counts, lists4, ovf_list, partial);

    // 6) finalize
    finalize_out<<<NNZ / 256, 256, 0, stream>>>(partial, gene_idx, b3, out);
}